// Round 21
// baseline (146.966 us; speedup 1.0000x reference)
//
#include <hip/hip_runtime.h>
#include <hip/hip_bf16.h>

#define M_DIM 4096
#define N_DIM 4096
#define K_DIM 4096
#define BM 256
#define BN 256
#define BK 64
#define NTILES (K_DIM / BK)   // 64

typedef __attribute__((ext_vector_type(8))) short short8;
typedef __attribute__((ext_vector_type(4))) float float4v;

__device__ __forceinline__ unsigned short f2bf(float f) {
    return __builtin_bit_cast(unsigned short, __float2bfloat16(f));
}

__device__ __forceinline__ void gload_lds16(const unsigned short* gsrc, unsigned short* lds) {
    __builtin_amdgcn_global_load_lds(
        (const __attribute__((address_space(1))) unsigned int*)gsrc,
        (__attribute__((address_space(3))) unsigned int*)lds,
        16, 0, 0);
}

#define BAR() do { asm volatile("" ::: "memory"); __builtin_amdgcn_s_barrier(); \
                   asm volatile("" ::: "memory"); } while (0)

// 16 MFMA (16x16x32), kk outer — r10/r15-verified
#define MFMA_Q(AR, BR, MO, NO)                                                   \
  do {                                                                           \
    __builtin_amdgcn_s_setprio(1);                                               \
    _Pragma("unroll") for (int kk = 0; kk < 2; ++kk)                             \
      _Pragma("unroll") for (int mf = 0; mf < 4; ++mf)                           \
        _Pragma("unroll") for (int nf = 0; nf < 2; ++nf)                         \
          acc[(MO) + mf][(NO) + nf] = __builtin_amdgcn_mfma_f32_16x16x32_bf16(   \
              AR[mf][kk], BR[nf][kk], acc[(MO) + mf][(NO) + nf], 0, 0, 0);       \
    __builtin_amdgcn_s_setprio(0);                                               \
  } while (0)

// ---------------- fp32 -> bf16 conversion + k-major blocking (r10 verbatim) -------
__global__ __launch_bounds__(256)
void cvt_blk(const float* __restrict__ X, const float* __restrict__ W,
             unsigned short* __restrict__ XB, unsigned short* __restrict__ WB) {
    const int nunits = 2 * 64 * 64;
    const int lane = threadIdx.x & 63;
    const int wglb = blockIdx.x * (blockDim.x >> 6) + (threadIdx.x >> 6);
    const int nw   = (gridDim.x * blockDim.x) >> 6;
    for (int u = wglb; u < nunits; u += nw) {
        const int mat = u >> 12;
        const int rem = u & 4095;
        const int r64 = rem >> 6, kt = rem & 63;
        const float* src = (mat ? W : X) + ((long)(r64 * 64 + lane) << 12) + kt * 64;
        unsigned short* dst = (mat ? WB : XB) + (long)rem * 4096;
#pragma unroll
        for (int j = 0; j < 8; ++j) {
            float4v a = *(const float4v*)(src + j * 8);
            float4v b = *(const float4v*)(src + j * 8 + 4);
            short8 o;
#pragma unroll
            for (int e = 0; e < 4; ++e) {
                o[e]     = (short)f2bf(a[e]);
                o[e + 4] = (short)f2bf(b[e]);
            }
            *(short8*)(dst + (j * 64 + lane) * 8) = o;
        }
    }
}

// -- 256x256 bf16 GEMM: r15 skeleton + register-neutral READ-AHEAD (operand age) --
// LDS: 8 regions x 16KB = 128KB; rho-block K-MAJOR (conflict-free, r10-verified).
// Stage slots, vmcnt(4), barrier topology = r15 VERBATIM. Only reads moved:
//   P1: read a1(t)   ; stage B-rho1(t+1)->buf^1          | BAR | Q00 (a0,b0: 1 win old)
//   P2: read b1(t)   ; stage B-rho0(t+1)->buf^1          | BAR | Q10 (a1: 1 win old)
//   P3:                stage A-rho0(t+2)->buf            | BAR | Q11 (b1: 1 win old)
//   P4:                stage A-rho1(t+2)->buf ; vmcnt(4) | BAR | Q01 ;
//       then read a0,b0 <- tile t+1 (buf^1; certified by vmcnt->BAR; registers
//       freed by Q01/Q10; HW register-WAR orders read-after-MFMA-consume)
// Read-region certification: early reads (a1@P1, b1@P2) target regions certified
// since BAR4(t-1) (vmcnt(4) there drained A(t),B(t) and older). Late reads target
// the just-certified t+1 regions. All stages unmoved from r15's verified ledger.
// Tail: t=62 -> vmcnt(0); t=63 -> no wait, no t+1 reads.
__global__ __launch_bounds__(512, 2)
void gemm_8ph(const unsigned short* __restrict__ XB, const unsigned short* __restrict__ WB,
              const float* __restrict__ Bv, float* __restrict__ O) {
    extern __shared__ unsigned short lds[];

    const int tid  = threadIdx.x;
    const int lane = tid & 63;
    const int wid  = tid >> 6;
    const int wm   = wid >> 2;   // 0..1 (M half)
    const int wn   = wid & 3;    // 0..3 (N quarter)

    // bijective XCD swizzle (nwg=256, %8==0)
    const int wg   = (blockIdx.x & 7) * 32 + (blockIdx.x >> 3);
    const int brow = (wg >> 4) * BM;
    const int bcol = (wg & 15) * BN;
    const int ar64 = (wg >> 4) * 4;
    const int br64 = (wg & 15) * 4;

    auto STAGE1 = [&](int mat, int half, int rho, int buf, int t) {
        const unsigned short* gsrc = (mat == 0)
            ? XB + ((long)((ar64 + half * 2 + rho) * 64 + t)) * 4096 + wid * 512 + lane * 8
            : WB + ((long)((br64 + half * 2 + rho) * 64 + t)) * 4096 + wid * 512 + lane * 8;
        unsigned short* reg = lds + (mat * 4 + half * 2 + buf) * 8192;
        gload_lds16(gsrc, reg + rho * 4096 + wid * 512);
    };

    // k-major fragment reads: chunk (kc = kk*4 + (lane>>4), row = f*16 + (lane&15))
    const int laneoff = (lane >> 4) * 512 + (lane & 15) * 8;

    auto LDA = [&](short8 (&dst)[4][2], int buf, int rho) {
        const unsigned short* base =
            lds + (wm * 2 + buf) * 8192 + rho * 4096 + laneoff;
#pragma unroll
        for (int mf = 0; mf < 4; ++mf) {
            dst[mf][0] = *(const short8*)(base + mf * 128);
            dst[mf][1] = *(const short8*)(base + 2048 + mf * 128);
        }
    };
    auto LDB = [&](short8 (&dst)[2][2], int buf, int nh) {
        const unsigned short* base =
            lds + (4 + (wn >> 1) * 2 + buf) * 8192 + (wn & 1) * 4096 + nh * 256 + laneoff;
#pragma unroll
        for (int nf = 0; nf < 2; ++nf) {
            dst[nf][0] = *(const short8*)(base + nf * 128);
            dst[nf][1] = *(const short8*)(base + 2048 + nf * 128);
        }
    };

    float4v acc[8][4] = {};
    short8 a0[4][2], a1[4][2], b0[2][2], b1[2][2];

    // ---- prologue: tile0 fully (8); drain; BAR; stage A(1)->buf1; pre-read a0/b0(0) ----
    STAGE1(0, 0, 0, 0, 0); STAGE1(0, 1, 0, 0, 0);
    STAGE1(0, 0, 1, 0, 0); STAGE1(0, 1, 1, 0, 0);
    STAGE1(1, 0, 0, 0, 0); STAGE1(1, 1, 0, 0, 0);
    STAGE1(1, 0, 1, 0, 0); STAGE1(1, 1, 1, 0, 0);
    asm volatile("s_waitcnt vmcnt(0)" ::: "memory");
    BAR();
    STAGE1(0, 0, 0, 1, 1); STAGE1(0, 1, 0, 1, 1);
    STAGE1(0, 0, 1, 1, 1); STAGE1(0, 1, 1, 1, 1);
    LDA(a0, 0, 0);
    LDB(b0, 0, 0);

    auto do_tile = [&](int buf, int t) {
        // P1: read a1(t) early; stage B-rho1(t+1)
        LDA(a1, buf, 1);
        if (t + 1 < NTILES) { STAGE1(1, 0, 1, buf ^ 1, t + 1); STAGE1(1, 1, 1, buf ^ 1, t + 1); }
        BAR();
        MFMA_Q(a0, b0, 0, 0);
        // P2: read b1(t) early; stage B-rho0(t+1)
        LDB(b1, buf, 1);
        if (t + 1 < NTILES) { STAGE1(1, 0, 0, buf ^ 1, t + 1); STAGE1(1, 1, 0, buf ^ 1, t + 1); }
        BAR();
        MFMA_Q(a1, b0, 4, 0);
        // P3: stage A-rho0(t+2)
        if (t + 2 < NTILES) { STAGE1(0, 0, 0, buf, t + 2); STAGE1(0, 1, 0, buf, t + 2); }
        BAR();
        MFMA_Q(a1, b1, 4, 2);
        // P4: stage A-rho1(t+2); counted vmcnt; BAR; Q01; late-read tile t+1's a0/b0
        if (t + 2 < NTILES) { STAGE1(0, 0, 1, buf, t + 2); STAGE1(0, 1, 1, buf, t + 2); }
        if (t + 2 < NTILES) {
            asm volatile("s_waitcnt vmcnt(4)" ::: "memory");
        } else if (t + 1 < NTILES) {
            asm volatile("s_waitcnt vmcnt(0)" ::: "memory");
        }
        BAR();
        MFMA_Q(a0, b1, 0, 2);
        if (t + 1 < NTILES) {
            LDA(a0, buf ^ 1, 0);   // regs freed by Q01 just issued; region certified
            LDB(b0, buf ^ 1, 0);   // regs freed since Q10; lands during P1(t+1)
        }
    };

    for (int it = 0; it < NTILES / 2; ++it) {
        do_tile(0, 2 * it);
        do_tile(1, 2 * it + 1);
    }

    // ---- epilogue: bias + store (D: col = lane&15, row = (lane>>4)*4 + r) ----
#pragma unroll
    for (int nf = 0; nf < 4; ++nf) {
        const int col = bcol + wn * 64 + nf * 16 + (lane & 15);
        const float bias = Bv[col];
#pragma unroll
        for (int mf = 0; mf < 8; ++mf) {
            const int row0 = brow + wm * 128 + mf * 16 + (lane >> 4) * 4;
#pragma unroll
            for (int r = 0; r < 4; ++r)
                O[(long)(row0 + r) * N_DIM + col] = acc[mf][nf][r] + bias;
        }
    }
}

extern "C" void kernel_launch(void* const* d_in, const int* in_sizes, int n_in,
                              void* d_out, int out_size, void* d_ws, size_t ws_size,
                              hipStream_t stream) {
    const float* X  = (const float*)d_in[0];
    const float* W  = (const float*)d_in[1];
    const float* Bv = (const float*)d_in[2];
    float* O        = (float*)d_out;

    unsigned short* XB = (unsigned short*)d_ws;
    unsigned short* WB = XB + (size_t)M_DIM * K_DIM;

    hipFuncSetAttribute((const void*)gemm_8ph,
                        hipFuncAttributeMaxDynamicSharedMemorySize, 131072);

    hipLaunchKernelGGL(cvt_blk, dim3(2048), dim3(256), 0, stream, X, W, XB, WB);
    hipLaunchKernelGGL(gemm_8ph, dim3((M_DIM / BM) * (N_DIM / BN)), dim3(512), 131072,
                       stream, XB, WB, Bv, O);
}

// Round 22
// 138.887 us; speedup vs baseline: 1.0582x; 1.0582x over previous
//
#include <hip/hip_runtime.h>
#include <hip/hip_bf16.h>

#define M_DIM 4096
#define N_DIM 4096
#define K_DIM 4096
#define BM 256
#define BN 256
#define BK 64
#define NTILES (K_DIM / BK)   // 64

typedef __attribute__((ext_vector_type(8))) short short8;
typedef __attribute__((ext_vector_type(4))) float float4v;

__device__ __forceinline__ unsigned short f2bf(float f) {
    return __builtin_bit_cast(unsigned short, __float2bfloat16(f));
}

__device__ __forceinline__ void gload_lds16(const unsigned short* gsrc, unsigned short* lds) {
    __builtin_amdgcn_global_load_lds(
        (const __attribute__((address_space(1))) unsigned int*)gsrc,
        (__attribute__((address_space(3))) unsigned int*)lds,
        16, 0, 0);
}

#define BAR() do { asm volatile("" ::: "memory"); __builtin_amdgcn_s_barrier(); \
                   asm volatile("" ::: "memory"); } while (0)

// 16 MFMA (16x16x32), kk outer — r10-verified
#define MFMA_Q(AR, BR, MO, NO)                                                   \
  do {                                                                           \
    __builtin_amdgcn_s_setprio(1);                                               \
    _Pragma("unroll") for (int kk = 0; kk < 2; ++kk)                             \
      _Pragma("unroll") for (int mf = 0; mf < 4; ++mf)                           \
        _Pragma("unroll") for (int nf = 0; nf < 2; ++nf)                         \
          acc[(MO) + mf][(NO) + nf] = __builtin_amdgcn_mfma_f32_16x16x32_bf16(   \
              AR[mf][kk], BR[nf][kk], acc[(MO) + mf][(NO) + nf], 0, 0, 0);       \
    __builtin_amdgcn_s_setprio(0);                                               \
  } while (0)

// ---------------- fp32 -> bf16 conversion + k-major blocking (r10 verbatim) -------
// ws per matrix: blocks (r64, kt); chunk (kc, row_l) at block*4096 + (kc*64+row_l)*8
// shorts = M[r64*64+row_l][kt*64+kc*8 .. +8].
__global__ __launch_bounds__(256)
void cvt_blk(const float* __restrict__ X, const float* __restrict__ W,
             unsigned short* __restrict__ XB, unsigned short* __restrict__ WB) {
    const int nunits = 2 * 64 * 64;
    const int lane = threadIdx.x & 63;
    const int wglb = blockIdx.x * (blockDim.x >> 6) + (threadIdx.x >> 6);
    const int nw   = (gridDim.x * blockDim.x) >> 6;
    for (int u = wglb; u < nunits; u += nw) {
        const int mat = u >> 12;
        const int rem = u & 4095;
        const int r64 = rem >> 6, kt = rem & 63;
        const float* src = (mat ? W : X) + ((long)(r64 * 64 + lane) << 12) + kt * 64;
        unsigned short* dst = (mat ? WB : XB) + (long)rem * 4096;
#pragma unroll
        for (int j = 0; j < 8; ++j) {
            float4v a = *(const float4v*)(src + j * 8);
            float4v b = *(const float4v*)(src + j * 8 + 4);
            short8 o;
#pragma unroll
            for (int e = 0; e < 4; ++e) {
                o[e]     = (short)f2bf(a[e]);
                o[e + 4] = (short)f2bf(b[e]);
            }
            *(short8*)(dst + (j * 64 + lane) * 8) = o;
        }
    }
}

// ------- 256x256 bf16 GEMM: k-major LDS (r10) + single-barrier pipeline (r5) -------
// FINAL (r15, reproduced at GEMM 114.4 us / 1200 TF, MfmaUtil 51%, 0 conflicts).
// LDS: 8 regions x 16KB = 128KB (idx = mat*4 + half*2 + buf); rho-block K-MAJOR:
// chunk (kc,row) at (kc*64+row)*16B. Staging = contiguous 1KB/wave gload_lds;
// reads conflict-free (SQ_LDS_BANK_CONFLICT=0, verified r10).
// ONE barrier per phase: reads+stages of phase p+1 overlap other waves' MFMA(p).
// WAR rule: overwrite region R only after a barrier that follows every wave's
// lgkm-wait on its reads of R (verified r5/r15/r18).
//   P1: read a0,b0; stage B-rho1(t+1)->buf^1 | BAR | Q00
//   P2: read a1   ; stage B-rho0(t+1)->buf^1 | BAR | Q10
//   P3: read b1   ; stage A-rho0(t+2)->buf   | BAR | Q11
//   P4:             stage A-rho1(t+2)->buf ; vmcnt(4) | BAR | Q01
// vmcnt(4) keeps the 4 newest (A(t+2)) in flight; drains B(t+1) + A(t+1).
__global__ __launch_bounds__(512, 2)
void gemm_8ph(const unsigned short* __restrict__ XB, const unsigned short* __restrict__ WB,
              const float* __restrict__ Bv, float* __restrict__ O) {
    extern __shared__ unsigned short lds[];

    const int tid  = threadIdx.x;
    const int lane = tid & 63;
    const int wid  = tid >> 6;
    const int wm   = wid >> 2;   // 0..1 (M half)
    const int wn   = wid & 3;    // 0..3 (N quarter)

    // bijective XCD swizzle (nwg=256, %8==0)
    const int wg   = (blockIdx.x & 7) * 32 + (blockIdx.x >> 3);
    const int brow = (wg >> 4) * BM;
    const int bcol = (wg & 15) * BN;
    const int ar64 = (wg >> 4) * 4;
    const int br64 = (wg & 15) * 4;

    auto STAGE1 = [&](int mat, int half, int rho, int buf, int t) {
        const unsigned short* gsrc = (mat == 0)
            ? XB + ((long)((ar64 + half * 2 + rho) * 64 + t)) * 4096 + wid * 512 + lane * 8
            : WB + ((long)((br64 + half * 2 + rho) * 64 + t)) * 4096 + wid * 512 + lane * 8;
        unsigned short* reg = lds + (mat * 4 + half * 2 + buf) * 8192;
        gload_lds16(gsrc, reg + rho * 4096 + wid * 512);
    };

    // k-major fragment reads: chunk (kc = kk*4 + (lane>>4), row = f*16 + (lane&15))
    const int laneoff = (lane >> 4) * 512 + (lane & 15) * 8;

    auto LDA = [&](short8 (&dst)[4][2], int buf, int rho) {
        const unsigned short* base =
            lds + (wm * 2 + buf) * 8192 + rho * 4096 + laneoff;
#pragma unroll
        for (int mf = 0; mf < 4; ++mf) {
            dst[mf][0] = *(const short8*)(base + mf * 128);
            dst[mf][1] = *(const short8*)(base + 2048 + mf * 128);
        }
    };
    auto LDB = [&](short8 (&dst)[2][2], int buf, int nh) {
        const unsigned short* base =
            lds + (4 + (wn >> 1) * 2 + buf) * 8192 + (wn & 1) * 4096 + nh * 256 + laneoff;
#pragma unroll
        for (int nf = 0; nf < 2; ++nf) {
            dst[nf][0] = *(const short8*)(base + nf * 128);
            dst[nf][1] = *(const short8*)(base + 2048 + nf * 128);
        }
    };

    float4v acc[8][4] = {};
    short8 a0[4][2], a1[4][2], b0[2][2], b1[2][2];

    // ---- prologue: tile0 fully (8) + tile1's A (4); vmcnt(4) keeps A(1) in flight ----
    STAGE1(0, 0, 0, 0, 0); STAGE1(0, 1, 0, 0, 0);
    STAGE1(0, 0, 1, 0, 0); STAGE1(0, 1, 1, 0, 0);
    STAGE1(1, 0, 0, 0, 0); STAGE1(1, 1, 0, 0, 0);
    STAGE1(1, 0, 1, 0, 0); STAGE1(1, 1, 1, 0, 0);
    STAGE1(0, 0, 0, 1, 1); STAGE1(0, 1, 0, 1, 1);
    STAGE1(0, 0, 1, 1, 1); STAGE1(0, 1, 1, 1, 1);
    asm volatile("s_waitcnt vmcnt(4)" ::: "memory");  // tile0's 8 landed
    BAR();

    auto do_tile = [&](int buf, int t) {
        // P1: reads a0,b0; stage B-rho1(t+1)
        LDA(a0, buf, 0);
        LDB(b0, buf, 0);
        if (t + 1 < NTILES) { STAGE1(1, 0, 1, buf ^ 1, t + 1); STAGE1(1, 1, 1, buf ^ 1, t + 1); }
        BAR();
        MFMA_Q(a0, b0, 0, 0);
        // P2: reads a1; stage B-rho0(t+1)
        LDA(a1, buf, 1);
        if (t + 1 < NTILES) { STAGE1(1, 0, 0, buf ^ 1, t + 1); STAGE1(1, 1, 0, buf ^ 1, t + 1); }
        BAR();
        MFMA_Q(a1, b0, 4, 0);
        // P3: reads b1; stage A-rho0(t+2)
        LDB(b1, buf, 1);
        if (t + 2 < NTILES) { STAGE1(0, 0, 0, buf, t + 2); STAGE1(0, 1, 0, buf, t + 2); }
        BAR();
        MFMA_Q(a1, b1, 4, 2);
        // P4: stage A-rho1(t+2); counted vmcnt -> tile t+1 ready after BAR
        if (t + 2 < NTILES) { STAGE1(0, 0, 1, buf, t + 2); STAGE1(0, 1, 1, buf, t + 2); }
        if (t + 2 < NTILES) {
            asm volatile("s_waitcnt vmcnt(4)" ::: "memory");
        } else if (t + 1 < NTILES) {
            asm volatile("s_waitcnt vmcnt(0)" ::: "memory");
        }
        BAR();
        MFMA_Q(a0, b1, 0, 2);
    };

    for (int it = 0; it < NTILES / 2; ++it) {
        do_tile(0, 2 * it);
        do_tile(1, 2 * it + 1);
    }

    // ---- epilogue: bias + store (D: col = lane&15, row = (lane>>4)*4 + r) ----
#pragma unroll
    for (int nf = 0; nf < 4; ++nf) {
        const int col = bcol + wn * 64 + nf * 16 + (lane & 15);
        const float bias = Bv[col];
#pragma unroll
        for (int mf = 0; mf < 8; ++mf) {
            const int row0 = brow + wm * 128 + mf * 16 + (lane >> 4) * 4;
#pragma unroll
            for (int r = 0; r < 4; ++r)
                O[(long)(row0 + r) * N_DIM + col] = acc[mf][nf][r] + bias;
        }
    }
}

extern "C" void kernel_launch(void* const* d_in, const int* in_sizes, int n_in,
                              void* d_out, int out_size, void* d_ws, size_t ws_size,
                              hipStream_t stream) {
    const float* X  = (const float*)d_in[0];
    const float* W  = (const float*)d_in[1];
    const float* Bv = (const float*)d_in[2];
    float* O        = (float*)d_out;

    unsigned short* XB = (unsigned short*)d_ws;
    unsigned short* WB = XB + (size_t)M_DIM * K_DIM;

    hipFuncSetAttribute((const void*)gemm_8ph,
                        hipFuncAttributeMaxDynamicSharedMemorySize, 131072);

    hipLaunchKernelGGL(cvt_blk, dim3(2048), dim3(256), 0, stream, X, W, XB, WB);
    hipLaunchKernelGGL(gemm_8ph, dim3((M_DIM / BM) * (N_DIM / BN)), dim3(512), 131072,
                       stream, XB, WB, Bv, O);
}